// Round 5
// baseline (199.400 us; speedup 1.0000x reference)
//
#include <hip/hip_runtime.h>
#include <cstdint>

typedef __attribute__((ext_vector_type(8))) short short8;     // 8 bf16 (4 VGPRs)
typedef __attribute__((ext_vector_type(4))) float floatx4;
typedef __attribute__((ext_vector_type(2))) unsigned int uintx2;
typedef __attribute__((ext_vector_type(4))) unsigned int uintx4;

#define CS 18                    // cell stride in words (16 kpair + 2 pad); 4*CS%32=8 -> bank spread
#define A_WORDS (4 * 32 * CS)    // 2304 words (9.2 KB)
#define B_WORDS (8 * 48 * CS)    // 6912 words (27.6 KB)  -> block total 36.9 KB -> 4 blocks/CU by LDS

__device__ __forceinline__ uint32_t pack2(float a, float b) {
    uint32_t ua = __builtin_bit_cast(uint32_t, a);
    uint32_t ub = __builtin_bit_cast(uint32_t, b);
    ua = (ua + 0x7FFFu + ((ua >> 16) & 1u)) >> 16;   // RNE (verified R1/R2/R4, absmax 0.5)
    ub = (ub + 0x7FFFu + ((ub >> 16) & 1u)) >> 16;
    return ua | (ub << 16);                           // lo = even channel, hi = odd channel
}

__device__ __forceinline__ short8 frag_ld(const uint32_t* p) {
    uintx2 lo = *(const uintx2*)p;        // ds_read_b64 (8B-aligned: CS even, offsets even)
    uintx2 hi = *(const uintx2*)(p + 2);
    uintx4 v = {lo.x, lo.y, hi.x, hi.y};
    return __builtin_bit_cast(short8, v);
}

// Core for di in [D0, D0+ND). Block = 4 waves = 4 h rows; wave = 32 w x ND di-offsets x 9 dj.
// Single LDS buffer, 2 barriers/chunk; loads issued before the pre-barrier so their latency
// overlaps the barrier wait; cross-block (3/CU) overlap hides the rest.
template<int D0, int ND>
__device__ __forceinline__ void corr_core(const float* __restrict__ f1b,
                                          const float* __restrict__ f2b,
                                          float* __restrict__ out,
                                          int b, int h0, int w0, int tid,
                                          uint32_t* ldsA, uint32_t* ldsB) {
    const int lane = tid & 63;
    const int wh   = tid >> 6;        // wave id == h sub-row (0..3)
    const int n15  = lane & 15;
    const int q    = lane >> 4;
    const int h    = h0 + wh;

    // ---- staging task precompute (chunk-invariant)
    // A: 256 tasks: t=tid -> w4=t&7, g=(t>>3)&7 (4 channels c=4g..4g+3 -> kp 2g,2g+1), row=t>>6
    const int aw4 = tid & 7, ag = (tid >> 3) & 7, arow = tid >> 6;
    const float* aP = f1b + (size_t)(4 * ag) * 8192 + (h0 + arow) * 128 + (w0 + 4 * aw4);
    uint32_t* aDst = &ldsA[(arow * 32 + 4 * aw4) * CS + 2 * ag];

    // B: 768 tasks: t=tid+256s -> w4=t%12, g=(t/12)&7, row=(t/12)>>3; gh = h0-4+D0+row
    const float* bP[3];
    uint32_t* bDst[3];
    uint32_t bMk[3];
#pragma unroll
    for (int s = 0; s < 3; ++s) {
        int t = tid + 256 * s;
        int w4 = t % 12;
        int rest = t / 12;
        int g = rest & 7, row = rest >> 3;
        int gh = h0 - 4 + D0 + row;
        int gw = w0 - 4 + 4 * w4;
        bool inb = ((unsigned)gh < 64u) && ((unsigned)gw < 128u);  // vec4 fully in or out
        bP[s]  = inb ? (f2b + (size_t)(4 * g) * 8192 + gh * 128 + gw) : f2b;
        bDst[s] = &ldsB[(row * 48 + 4 * w4) * CS + 2 * g];
        bMk[s] = inb ? 0xFFFFFFFFu : 0u;
    }

    floatx4 acc[ND][4];
#pragma unroll
    for (int di = 0; di < ND; ++di)
#pragma unroll
        for (int t = 0; t < 4; ++t)
            acc[di][t] = (floatx4){0.f, 0.f, 0.f, 0.f};

    for (int ch = 0; ch < 8; ++ch) {
        const size_t coff = (size_t)(ch * 32) * 8192;

        // ---- issue all loads for this chunk (latency overlaps the barrier wait below)
        floatx4 av[4], bv[3][4];
#pragma unroll
        for (int k = 0; k < 4; ++k)
            av[k] = *(const floatx4*)(aP + coff + (size_t)k * 8192);
#pragma unroll
        for (int s = 0; s < 3; ++s)
#pragma unroll
            for (int k = 0; k < 4; ++k)
                bv[s][k] = *(const floatx4*)(bP[s] + coff + (size_t)k * 8192);

        if (ch) __syncthreads();      // buffer free: all waves done computing chunk ch-1

        // ---- pack + b64 LDS writes (2 kp-words per write)
#pragma unroll
        for (int i = 0; i < 4; ++i) {
            uintx2 wv = { pack2(av[0][i], av[1][i]), pack2(av[2][i], av[3][i]) };
            *(uintx2*)(aDst + i * CS) = wv;
        }
#pragma unroll
        for (int s = 0; s < 3; ++s)
#pragma unroll
            for (int i = 0; i < 4; ++i) {
                uintx2 wv = { pack2(bv[s][0][i], bv[s][1][i]) & bMk[s],
                              pack2(bv[s][2][i], bv[s][3][i]) & bMk[s] };
                *(uintx2*)(bDst[s] + i * CS) = wv;
            }
        __syncthreads();              // buffer ready

        // ---- compute: A[m=lane&15][k=q*8+j]; B[k][n=lane&15]
        const uint32_t* pa = &ldsA[(wh * 32 + n15) * CS + 4 * q];
        short8 a0 = frag_ld(pa);                  // m -> w0 + n15
        short8 a1 = frag_ld(pa + 16 * CS);        // m -> w0 + 16 + n15
#pragma unroll
        for (int di = 0; di < ND; ++di) {
            const uint32_t* pb = &ldsB[((wh + di) * 48 + n15) * CS + 4 * q];
            short8 b0 = frag_ld(pb);              // cols 0..15  (gw = w0-4 ..)
            short8 b1 = frag_ld(pb + 16 * CS);    // cols 16..31
            short8 b2 = frag_ld(pb + 32 * CS);    // cols 32..47
            acc[di][0] = __builtin_amdgcn_mfma_f32_16x16x32_bf16(a0, b0, acc[di][0], 0, 0, 0);
            acc[di][1] = __builtin_amdgcn_mfma_f32_16x16x32_bf16(a0, b1, acc[di][1], 0, 0, 0);
            acc[di][2] = __builtin_amdgcn_mfma_f32_16x16x32_bf16(a1, b1, acc[di][2], 0, 0, 0);
            acc[di][3] = __builtin_amdgcn_mfma_f32_16x16x32_bf16(a1, b2, acc[di][3], 0, 0, 0);
        }
    }

    // ---- epilogue: band extraction (verified R1/R2/R4).
    // D[m'=q*4+r][n'=lane&15]; dj = (Bt-At)*16 + n' - m'; w = w0 + At*16 + m'; d = (D0+di)*9+dj.
    const int At[4] = {0, 0, 1, 1};
    const int Bt[4] = {0, 1, 1, 2};
#pragma unroll
    for (int di = 0; di < ND; ++di) {
#pragma unroll
        for (int t = 0; t < 4; ++t) {
#pragma unroll
            for (int r = 0; r < 4; ++r) {
                int mp = 4 * q + r;
                int dj = (Bt[t] - At[t]) * 16 + n15 - mp;
                if (dj >= 0 && dj <= 8) {
                    int w = w0 + At[t] * 16 + mp;
                    size_t idx = (((size_t)b * 81 + (size_t)((D0 + di) * 9 + dj)) * 64 + h) * 128 + w;
                    out[idx] = acc[di][t][r];
                }
            }
        }
    }
}

__global__ __launch_bounds__(256, 3)
void corr_kernel(const float* __restrict__ f1, const float* __restrict__ f2,
                 float* __restrict__ out) {
    __shared__ uint32_t ldsA[A_WORDS];
    __shared__ uint32_t ldsB[B_WORDS];

    const int tid = threadIdx.x;
    const int bid = blockIdx.x;
    const int b    = bid & 7;          // batch in low bits -> XCD partition (L2 locality)
    const int rest = bid >> 3;
    const int half = rest & 1;         // di-half
    const int ht   = (rest >> 1) & 15; // h tile -> h0 = 4*ht
    const int wt   = rest >> 5;        // w tile -> w0 = 32*wt

    const int w0 = wt * 32;
    const int h0 = ht * 4;

    const float* f1b = f1 + (size_t)b * 256 * 8192;
    const float* f2b = f2 + (size_t)b * 256 * 8192;

    if (half == 0)
        corr_core<0, 5>(f1b, f2b, out, b, h0, w0, tid, ldsA, ldsB);
    else
        corr_core<5, 4>(f1b, f2b, out, b, h0, w0, tid, ldsA, ldsB);
}

extern "C" void kernel_launch(void* const* d_in, const int* in_sizes, int n_in,
                              void* d_out, int out_size, void* d_ws, size_t ws_size,
                              hipStream_t stream) {
    const float* f1 = (const float*)d_in[0];
    const float* f2 = (const float*)d_in[1];
    float* out = (float*)d_out;
    // grid: 8 batches x 2 di-halves x 16 h-tiles x 4 w-tiles = 1024 blocks (~3 resident/CU)
    corr_kernel<<<dim3(1024), dim3(256), 0, stream>>>(f1, f2, out);
}

// Round 6
// 189.585 us; speedup vs baseline: 1.0518x; 1.0518x over previous
//
#include <hip/hip_runtime.h>
#include <cstdint>

typedef __attribute__((ext_vector_type(8))) short short8;     // 8 bf16 (4 VGPRs)
typedef __attribute__((ext_vector_type(4))) float floatx4;
typedef __attribute__((ext_vector_type(2))) unsigned int uintx2;
typedef __attribute__((ext_vector_type(4))) unsigned int uintx4;

#define CS 18                    // cell stride in words (16 kpair + 2 pad); 4*CS%32=8 -> bank spread
#define A_WORDS (4 * 32 * CS)    // 2304 words (9.2 KB)
#define B_WORDS (8 * 48 * CS)    // 6912 words (27.6 KB)  -> block total 36.9 KB

__device__ __forceinline__ uint32_t pack2(float a, float b) {
    uint32_t ua = __builtin_bit_cast(uint32_t, a);
    uint32_t ub = __builtin_bit_cast(uint32_t, b);
    ua = (ua + 0x7FFFu + ((ua >> 16) & 1u)) >> 16;   // RNE (verified R1/R2/R4/R5, absmax 0.5)
    ub = (ub + 0x7FFFu + ((ub >> 16) & 1u)) >> 16;
    return ua | (ub << 16);                           // lo = even channel, hi = odd channel
}

__device__ __forceinline__ short8 frag_ld(const uint32_t* p) {
    uintx2 lo = *(const uintx2*)p;        // ds_read_b64 (8B-aligned: CS even, offsets even)
    uintx2 hi = *(const uintx2*)(p + 2);
    uintx4 v = {lo.x, lo.y, hi.x, hi.y};
    return __builtin_bit_cast(short8, v);
}

// Core for di in [D0, D0+ND). Block = 4 waves = 4 h rows; wave = 32 w x ND di x 9 dj.
// Pipeline per chunk: compute(ch-1) -> issue loads(ch) -> barrier -> pack/write(ch) -> barrier.
// Loads are in flight only across the barrier (no parking across compute -> low VGPR);
// the vmcnt stall at pack is hidden by the other resident barrier groups (3 blocks/CU).
template<int D0, int ND>
__device__ __forceinline__ void corr_core(const float* __restrict__ f1b,
                                          const float* __restrict__ f2b,
                                          float* __restrict__ out,
                                          int b, int h0, int w0, int tid,
                                          uint32_t* ldsA, uint32_t* ldsB) {
    const int lane = tid & 63;
    const int wh   = tid >> 6;        // wave id == h sub-row (0..3)
    const int n15  = lane & 15;
    const int q    = lane >> 4;
    const int h    = h0 + wh;

    // ---- staging task precompute (chunk-invariant)
    // A: 256 tasks: t=tid -> w4=t&7, g=(t>>3)&7 (channels 4g..4g+3 -> kp 2g,2g+1), row=t>>6
    const int aw4 = tid & 7, ag = (tid >> 3) & 7, arow = tid >> 6;
    const float* aP = f1b + (size_t)(4 * ag) * 8192 + (h0 + arow) * 128 + (w0 + 4 * aw4);
    uint32_t* aDst = &ldsA[(arow * 32 + 4 * aw4) * CS + 2 * ag];

    // B: 768 tasks: t=tid+256s -> w4=t%12, g=(t/12)&7, row=(t/12)>>3; gh = h0-4+D0+row
    const float* bP[3];
    uint32_t* bDst[3];
    uint32_t bMk[3];
#pragma unroll
    for (int s = 0; s < 3; ++s) {
        int t = tid + 256 * s;
        int w4 = t % 12;
        int rest = t / 12;
        int g = rest & 7, row = rest >> 3;
        int gh = h0 - 4 + D0 + row;
        int gw = w0 - 4 + 4 * w4;
        bool inb = ((unsigned)gh < 64u) && ((unsigned)gw < 128u);  // vec4 fully in or out
        bP[s]  = inb ? (f2b + (size_t)(4 * g) * 8192 + gh * 128 + gw) : f2b;
        bDst[s] = &ldsB[(row * 48 + 4 * w4) * CS + 2 * g];
        bMk[s] = inb ? 0xFFFFFFFFu : 0u;
    }

    floatx4 acc[ND][4];
#pragma unroll
    for (int di = 0; di < ND; ++di)
#pragma unroll
        for (int t = 0; t < 4; ++t)
            acc[di][t] = (floatx4){0.f, 0.f, 0.f, 0.f};

    for (int ch = 0; ch <= 8; ++ch) {
        // ---- compute previous chunk from LDS (no outstanding loads alive here)
        if (ch > 0) {
            const uint32_t* pa = &ldsA[(wh * 32 + n15) * CS + 4 * q];
            short8 a0 = frag_ld(pa);                  // m -> w0 + n15
            short8 a1 = frag_ld(pa + 16 * CS);        // m -> w0 + 16 + n15
#pragma unroll
            for (int di = 0; di < ND; ++di) {
                const uint32_t* pb = &ldsB[((wh + di) * 48 + n15) * CS + 4 * q];
                short8 b0 = frag_ld(pb);              // cols 0..15  (gw = w0-4 ..)
                short8 b1 = frag_ld(pb + 16 * CS);    // cols 16..31
                short8 b2 = frag_ld(pb + 32 * CS);    // cols 32..47
                acc[di][0] = __builtin_amdgcn_mfma_f32_16x16x32_bf16(a0, b0, acc[di][0], 0, 0, 0);
                acc[di][1] = __builtin_amdgcn_mfma_f32_16x16x32_bf16(a0, b1, acc[di][1], 0, 0, 0);
                acc[di][2] = __builtin_amdgcn_mfma_f32_16x16x32_bf16(a1, b1, acc[di][2], 0, 0, 0);
                acc[di][3] = __builtin_amdgcn_mfma_f32_16x16x32_bf16(a1, b2, acc[di][3], 0, 0, 0);
            }
        }

        if (ch < 8) {
            const size_t coff = (size_t)(ch * 32) * 8192;
            // issue loads; they fly across the barrier below
            floatx4 av[4], bv[3][4];
#pragma unroll
            for (int k = 0; k < 4; ++k)
                av[k] = *(const floatx4*)(aP + coff + (size_t)k * 8192);
#pragma unroll
            for (int s = 0; s < 3; ++s)
#pragma unroll
                for (int k = 0; k < 4; ++k)
                    bv[s][k] = *(const floatx4*)(bP[s] + coff + (size_t)k * 8192);

            if (ch > 0) __syncthreads();   // buffer free: all waves done computing ch-1

            // pack + b64 LDS writes (vmcnt wait lands here; other blocks' waves fill)
#pragma unroll
            for (int i = 0; i < 4; ++i) {
                uintx2 wv = { pack2(av[0][i], av[1][i]), pack2(av[2][i], av[3][i]) };
                *(uintx2*)(aDst + i * CS) = wv;
            }
#pragma unroll
            for (int s = 0; s < 3; ++s)
#pragma unroll
                for (int i = 0; i < 4; ++i) {
                    uintx2 wv = { pack2(bv[s][0][i], bv[s][1][i]) & bMk[s],
                                  pack2(bv[s][2][i], bv[s][3][i]) & bMk[s] };
                    *(uintx2*)(bDst[s] + i * CS) = wv;
                }
            __syncthreads();               // buffer ready for compute at ch+1
        }
    }

    // ---- epilogue: band extraction (verified R1/R2/R4/R5).
    // D[m'=q*4+r][n'=lane&15]; dj = (Bt-At)*16 + n' - m'; w = w0 + At*16 + m'; d = (D0+di)*9+dj.
    const int At[4] = {0, 0, 1, 1};
    const int Bt[4] = {0, 1, 1, 2};
#pragma unroll
    for (int di = 0; di < ND; ++di) {
#pragma unroll
        for (int t = 0; t < 4; ++t) {
#pragma unroll
            for (int r = 0; r < 4; ++r) {
                int mp = 4 * q + r;
                int dj = (Bt[t] - At[t]) * 16 + n15 - mp;
                if (dj >= 0 && dj <= 8) {
                    int w = w0 + At[t] * 16 + mp;
                    size_t idx = (((size_t)b * 81 + (size_t)((D0 + di) * 9 + dj)) * 64 + h) * 128 + w;
                    out[idx] = acc[di][t][r];
                }
            }
        }
    }
}

__global__ __launch_bounds__(256, 3)
void corr_kernel(const float* __restrict__ f1, const float* __restrict__ f2,
                 float* __restrict__ out) {
    __shared__ uint32_t ldsA[A_WORDS];
    __shared__ uint32_t ldsB[B_WORDS];

    const int tid = threadIdx.x;
    const int bid = blockIdx.x;
    const int b    = bid & 7;          // batch in low bits -> XCD partition (L2 locality)
    const int rest = bid >> 3;
    const int half = rest & 1;         // di-half
    const int ht   = (rest >> 1) & 15; // h tile -> h0 = 4*ht
    const int wt   = rest >> 5;        // w tile -> w0 = 32*wt

    const int w0 = wt * 32;
    const int h0 = ht * 4;

    const float* f1b = f1 + (size_t)b * 256 * 8192;
    const float* f2b = f2 + (size_t)b * 256 * 8192;

    if (half == 0)
        corr_core<0, 5>(f1b, f2b, out, b, h0, w0, tid, ldsA, ldsB);
    else
        corr_core<5, 4>(f1b, f2b, out, b, h0, w0, tid, ldsA, ldsB);
}

extern "C" void kernel_launch(void* const* d_in, const int* in_sizes, int n_in,
                              void* d_out, int out_size, void* d_ws, size_t ws_size,
                              hipStream_t stream) {
    const float* f1 = (const float*)d_in[0];
    const float* f2 = (const float*)d_in[1];
    float* out = (float*)d_out;
    // grid: 8 batches x 2 di-halves x 16 h-tiles x 4 w-tiles = 1024 blocks (~3 resident/CU)
    corr_kernel<<<dim3(1024), dim3(256), 0, stream>>>(f1, f2, out);
}